// Round 3
// baseline (126.736 us; speedup 1.0000x reference)
//
#include <hip/hip_runtime.h>
#include <math.h>

// Hit-miss transform: out[i][j] = min_{di,dj}(x[i+di][j+dj] - Khit[di][dj])
//                               - max_{di,dj}(x[i+di][j+dj] - Kmiss[di][dj])
// H=W=4096 fp32 input, 5x5 kernels, output 4092x4092 fp32.
//
// R6: packed-fp32 subtracts. R4/R5 showed time is VALU-issue-bound
// (VALUBusy 73% = 30.3us of 41.5us wall) and that loop-nest shape is not a
// lever (compiler re-schedules to the same engine; VGPR stayed ~32-36).
// Core math was 78 ops/pixel, 50 of them subtracts in hit/miss pairs on the
// same input value. One v_pk_add_f32 (VOP3P) computes BOTH:
//   d.lo = v[e]-wh[k], d.hi = v[e]-wm[k]
// using op_sel to broadcast the input half (no shuffle movs: rows loaded as
// ulonglong2 so VGPR pairs are natural) and an SGPR weight pair (wh,wm)
// packed once per thread. 50 -> 25 sub instrs/pixel, core 78 -> ~54 (-31%).
// Identical IEEE ops and reduction order -> bit-exact output.
// Grid packing kept: 4 x 1023 = 4092 blocks = 2 exact resident rounds.

constexpr int KS  = 5;
constexpr int WW  = 4096;
constexpr int HO  = 4092;
constexpr int WO  = 4092;
constexpr int CG  = WO / 4;   // 1023 column groups
constexpr int RPT = 4;        // output rows per thread (4092 = 4*1023)

__device__ __forceinline__ float min3f(float a, float b, float c) {
    float d;
    asm("v_min3_f32 %0, %1, %2, %3" : "=v"(d) : "v"(a), "v"(b), "v"(c));
    return d;
}
__device__ __forceinline__ float max3f(float a, float b, float c) {
    float d;
    asm("v_max3_f32 %0, %1, %2, %3" : "=v"(d) : "v"(a), "v"(b), "v"(c));
    return d;
}

// (v[sel] - w.lo, v[sel] - w.hi) in one VOP3P instruction.
// vpair: VGPR pair holding (v_even, v_odd); sel picks the half (compile-time
// constant after unroll -> branch folds). w: SGPR pair (wh in lo, wm in hi).
__device__ __forceinline__ float2 pksub(int sel, uint64_t vpair, uint64_t w) {
    uint64_t r;
    if (sel == 0) {
        asm("v_pk_add_f32 %0, %1, %2 op_sel:[0,0] op_sel_hi:[0,1] neg_lo:[0,1] neg_hi:[0,1]"
            : "=v"(r) : "v"(vpair), "s"(w));
    } else {
        asm("v_pk_add_f32 %0, %1, %2 op_sel:[1,0] op_sel_hi:[1,1] neg_lo:[0,1] neg_hi:[0,1]"
            : "=v"(r) : "v"(vpair), "s"(w));
    }
    union { uint64_t u; float2 f; } cvt;
    cvt.u = r;
    return cvt.f;   // .x = hit-side value, .y = miss-side value
}

__global__ __launch_bounds__(256) void hitmiss_kernel(
    const float* __restrict__ x,
    const float* __restrict__ kh,
    const float* __restrict__ km,
    float* __restrict__ out)
{
    const int cg = blockIdx.x * blockDim.x + threadIdx.x;  // column group
    if (cg >= CG) return;
    const int j0 = cg * 4;
    const int r0 = blockIdx.y * RPT;

    // Weight pairs (wh[k] lo, wm[k] hi), uniform -> SGPR pairs via SALU.
    uint64_t wp[KS * KS];
#pragma unroll
    for (int k = 0; k < KS * KS; ++k) {
        wp[k] = ((uint64_t)__float_as_uint(km[k]) << 32) |
                (uint64_t)__float_as_uint(kh[k]);
    }

    const float* base = x + (size_t)r0 * WW + j0;

    // Accumulators for RPT output rows x 4 pixels.
    float mn[RPT][4], mx[RPT][4];

#pragma unroll
    for (int i = 0; i < RPT + 4; ++i) {
        // Row i as four natural VGPR pairs (v0,v1),(v2,v3),(v4,v5),(v6,v7):
        // two dwordx4 loads reinterpreted as ulonglong2 -> zero shuffle movs.
        ulonglong2 A = *reinterpret_cast<const ulonglong2*>(base + (size_t)i * WW);
        ulonglong2 B = *reinterpret_cast<const ulonglong2*>(base + (size_t)i * WW + 4);
        const uint64_t pr[4] = {A.x, A.y, B.x, B.y};

#pragma unroll
        for (int o = 0; o < RPT; ++o) {
            const int di = i - o;              // static after unroll
            if (di < 0 || di > KS - 1) continue;
#pragma unroll
            for (int p = 0; p < 4; ++p) {
                // 5 packed subs: element e = p+j, weight row di.
                const float2 t0 = pksub((p + 0) & 1, pr[(p + 0) >> 1], wp[di * KS + 0]);
                const float2 t1 = pksub((p + 1) & 1, pr[(p + 1) >> 1], wp[di * KS + 1]);
                const float2 t2 = pksub((p + 2) & 1, pr[(p + 2) >> 1], wp[di * KS + 2]);
                const float2 t3 = pksub((p + 3) & 1, pr[(p + 3) >> 1], wp[di * KS + 3]);
                const float2 t4 = pksub((p + 4) & 1, pr[(p + 4) >> 1], wp[di * KS + 4]);

                const float m5 = min3f(t3.x, t4.x, min3f(t0.x, t1.x, t2.x));
                const float x5 = max3f(t3.y, t4.y, max3f(t0.y, t1.y, t2.y));
                if (di == 0) {
                    mn[o][p] = m5;
                    mx[o][p] = x5;
                } else {
                    mn[o][p] = fminf(mn[o][p], m5);
                    mx[o][p] = fmaxf(mx[o][p], x5);
                }
            }
        }

        // Output row o = i-4 complete; store and free.
        if (i >= KS - 1) {
            const int o = i - (KS - 1);
            float4 oo;
            oo.x = mn[o][0] - mx[o][0];
            oo.y = mn[o][1] - mx[o][1];
            oo.z = mn[o][2] - mx[o][2];
            oo.w = mn[o][3] - mx[o][3];
            *reinterpret_cast<float4*>(out + (size_t)(r0 + o) * WO + j0) = oo;
        }
    }
}

extern "C" void kernel_launch(void* const* d_in, const int* in_sizes, int n_in,
                              void* d_out, int out_size, void* d_ws, size_t ws_size,
                              hipStream_t stream) {
    const float* x  = (const float*)d_in[0];
    const float* kh = (const float*)d_in[1];
    const float* km = (const float*)d_in[2];
    float* out = (float*)d_out;

    dim3 block(256, 1, 1);
    dim3 grid((CG + 255) / 256, HO / RPT, 1);  // 4 x 1023 = 4092 blocks ~= 2 x 2048 resident
    hipLaunchKernelGGL(hitmiss_kernel, grid, block, 0, stream, x, kh, km, out);
}